// Round 18
// baseline (45.724 us; speedup 1.0000x reference)
//
#include <hip/hip_runtime.h>
#include <math.h>

#define ALPHA 0.001f
#define GAMMA 0.01f
#define DD 784
#define TD 1568          // 2*D floats per template row
#define MM 256
#define BB 1024
#define NCLS 10
#define NBLK 1024        // 128 rowgroups x 8 template-octet groups

// ws layout:
//   f32[0..255] partial min | f32[256..511] partial max
//   f32[512..767] scale[m] | f32[768] min | f32[769] 1/(max-min+1e-10)
//   i32[1024..1279] tsum[m]
//   i32[1536..2559] rowsum[row]
//   byte 16384:  TRANSPOSED u8 templates  tT4[j4][m]   98*256*16B  = 392 KB
//   byte 540672: TRANSPOSED u8 coded      cT4[j4][row] 98*1024*16B = 1.57 MB

#define TMPL_OFF 16384
#define CODED_OFF 540672

static __device__ __forceinline__ unsigned sad_u8(unsigned a, unsigned b, unsigned c) {
  unsigned d;
  asm("v_sad_u8 %0, %1, %2, %3" : "=v"(d) : "v"(a), "v"(b), "v"(c));
  return d;
}

static __device__ __forceinline__ unsigned q8(float v) {
  return (unsigned)(v * 255.f + 0.5f);   // v in [0,1]
}

__global__ __launch_bounds__(256) void k_minmax(const float* __restrict__ x,
                                                float* __restrict__ ws,
                                                int* __restrict__ out_bits) {
  const float4* x4 = (const float4*)x;
  const int n4 = BB * DD / 4;
  int tid = blockIdx.x * 256 + threadIdx.x;
  if (tid < BB * NCLS) out_bits[tid] = (int)0xFF800000;  // -inf each launch
  float mn = 1e30f, mx = -1e30f;
  for (int i = tid; i < n4; i += 256 * 256) {
    float4 v = x4[i];
    mn = fminf(mn, fminf(fminf(v.x, v.y), fminf(v.z, v.w)));
    mx = fmaxf(mx, fmaxf(fmaxf(v.x, v.y), fmaxf(v.z, v.w)));
  }
#pragma unroll
  for (int off = 32; off; off >>= 1) {
    mn = fminf(mn, __shfl_xor(mn, off, 64));
    mx = fmaxf(mx, __shfl_xor(mx, off, 64));
  }
  __shared__ float smn[4], smx[4];
  int lane = threadIdx.x & 63, wid = threadIdx.x >> 6;
  if (lane == 0) { smn[wid] = mn; smx[wid] = mx; }
  __syncthreads();
  if (threadIdx.x == 0) {
    mn = fminf(fminf(smn[0], smn[1]), fminf(smn[2], smn[3]));
    mx = fmaxf(fmaxf(smx[0], smx[1]), fmaxf(smx[2], smx[3]));
    ws[blockIdx.x] = mn;
    ws[256 + blockIdx.x] = mx;
  }
}

// 16 blocks x 256 thr; block b handles templates b*16..b*16+15, writing the
// TRANSPOSED quantized layout tT4[j4][m] plus scale[m], tsum[m].
// Block 0 additionally finalizes the global min/max stats first (saves the
// separate k_stats launch; k_code runs after and reads ws[768..769]).
__global__ __launch_bounds__(256) void k_denom(const float* __restrict__ T,
                                               const int* __restrict__ committed,
                                               const int* __restrict__ counts,
                                               float* __restrict__ ws) {
  __shared__ float fs16[16][17];
  __shared__ int   is16[16][17];
  __shared__ float sred[8];
  int tid = threadIdx.x;
  int b = blockIdx.x;

  if (b == 0) {   // ---- stats finalize (block-uniform branch) ----
    float mn = ws[tid], mx = ws[256 + tid];
#pragma unroll
    for (int off = 32; off; off >>= 1) {
      mn = fminf(mn, __shfl_xor(mn, off, 64));
      mx = fmaxf(mx, __shfl_xor(mx, off, 64));
    }
    int lane = tid & 63, wid = tid >> 6;
    if (lane == 0) { sred[wid] = mn; sred[4 + wid] = mx; }
    __syncthreads();
    if (tid == 0) {
      mn = fminf(fminf(sred[0], sred[1]), fminf(sred[2], sred[3]));
      mx = fmaxf(fmaxf(sred[4], sred[5]), fmaxf(sred[6], sred[7]));
      ws[768] = mn;
      ws[769] = 1.0f / (mx - mn + 1e-10f);
    }
  }

  int ml = tid & 15;          // template within block
  int jp = tid >> 4;          // j4 sub-index
  int m = b * 16 + ml;
  uint4* tT4 = (uint4*)((char*)ws + TMPL_OFF);
  const float4* tp = (const float4*)T + (size_t)m * (TD / 4);
  float fsum = 0.f;
  int isum = 0;
#pragma unroll
  for (int jj = 0; jj < 7; ++jj) {
    int j4 = jj * 16 + jp;
    if (j4 < 98) {
      unsigned w[4];
#pragma unroll
      for (int d = 0; d < 4; ++d) {
        float4 f = tp[j4 * 4 + d];
        fsum += (f.x + f.y) + (f.z + f.w);
        unsigned b0 = q8(f.x), b1 = q8(f.y), b2 = q8(f.z), b3 = q8(f.w);
        isum += (int)(b0 + b1 + b2 + b3);
        w[d] = b0 | (b1 << 8) | (b2 << 16) | (b3 << 24);
      }
      tT4[(size_t)j4 * 256 + m] = make_uint4(w[0], w[1], w[2], w[3]);
    }
  }
  fs16[ml][jp] = fsum;
  is16[ml][jp] = isum;
  __syncthreads();
  if (tid < 16) {   // ordered, deterministic reduction
    int m2 = b * 16 + tid;
    float s = 0.f; int is = 0;
#pragma unroll
    for (int k = 0; k < 16; ++k) { s += fs16[tid][k]; is += is16[tid][k]; }
    float denom = ALPHA + s + GAMMA * (float)counts[m2];
    ws[512 + m2] = committed[m2] ? (1.0f / denom) : -1.0f;
    ((int*)ws)[1024 + m2] = is;
  }
}

// 64 blocks x 256 thr; block handles rows b*16..b*16+15 -> transposed
// quantized complement-coded layout cT4[j4][row] + rowsum[row].
__global__ __launch_bounds__(256) void k_code(const float* __restrict__ x,
                                              float* __restrict__ ws) {
  __shared__ int rsum[16];
  int tid = threadIdx.x;
  if (tid < 16) rsum[tid] = 0;
  __syncthreads();
  float fmn = ws[768], finv = ws[769];
  float na = finv, nb = -fmn * finv;
  int rl = tid & 15, jp = tid >> 4;
  int row = blockIdx.x * 16 + rl;
  uint4* cT4 = (uint4*)((char*)ws + CODED_OFF);
  const float4* xr = (const float4*)x + (size_t)row * (DD / 4);
  int isum = 0;
#pragma unroll
  for (int jj = 0; jj < 7; ++jj) {
    int j4 = jj * 16 + jp;
    if (j4 < 98) {
      unsigned w[4];
      int comp = (j4 >= 49);
      int jb = comp ? (j4 - 49) : j4;
#pragma unroll
      for (int d = 0; d < 4; ++d) {
        float4 f = xr[jb * 4 + d];
        float v0 = na * f.x + nb, v1 = na * f.y + nb;
        float v2 = na * f.z + nb, v3 = na * f.w + nb;
        if (comp) { v0 = 1.f - v0; v1 = 1.f - v1; v2 = 1.f - v2; v3 = 1.f - v3; }
        unsigned b0 = q8(v0), b1 = q8(v1), b2 = q8(v2), b3 = q8(v3);
        isum += (int)(b0 + b1 + b2 + b3);
        w[d] = b0 | (b1 << 8) | (b2 << 16) | (b3 << 24);
      }
      cT4[(size_t)j4 * 1024 + row] = make_uint4(w[0], w[1], w[2], w[3]);
    }
  }
  atomicAdd(&rsum[rl], isum);
  __syncthreads();
  if (tid < 16) ((int*)ws)[1536 + blockIdx.x * 16 + tid] = rsum[tid];
}

// grid: 1024 = 128 rowgroups x 8 template-octet-groups; 256 thr = 4 waves.
// PAIR-PER-LANE: lane owns ONE (row, template) pair completely; reduction
// axis is lane-local -> zero cross-lane ops (no DPP/readlane/scatter).
// Per wave-iter: 2 loads (8 distinct 16B chunks each, contiguous 128B,
// L1-broadcast) + 4 v_sad_u8. 98 iters -> 64 finished outputs per wave.
__global__ __launch_bounds__(256) void k_main(const int* __restrict__ labels,
                                              const float* __restrict__ ws,
                                              int* __restrict__ out_bits) {
  __shared__ int clsmax[8][NCLS];
  int tid = threadIdx.x;
  int lane = tid & 63, wid = tid >> 6;
  int rg = blockIdx.x >> 3;
  int tgq = blockIdx.x & 7;
  int row0 = rg * 8;
  int m0 = tgq * 32 + wid * 8;
  int r = lane >> 3, tl = lane & 7;
  int row = row0 + r;
  int m = m0 + tl;

  if (tid < 8 * NCLS) clsmax[tid / NCLS][tid % NCLS] = (int)0xFF800000;

  const uint4* cT4 = (const uint4*)((const char*)ws + CODED_OFF);
  const uint4* tT4 = (const uint4*)((const char*)ws + TMPL_OFF);

  unsigned acc = 0;
#pragma unroll 7
  for (int j4 = 0; j4 < 98; ++j4) {
    uint4 cv = cT4[(size_t)j4 * 1024 + row];
    uint4 tv = tT4[(size_t)j4 * 256 + m];
    acc = sad_u8(cv.x, tv.x, acc);
    acc = sad_u8(cv.y, tv.y, acc);
    acc = sad_u8(cv.z, tv.z, acc);
    acc = sad_u8(cv.w, tv.w, acc);
  }

  int myrow = ((const int*)ws)[1536 + row];
  int mts   = ((const int*)ws)[1024 + m];
  float sc  = ws[512 + m];
  int lb    = labels[m];
  float vout = (float)(myrow + mts - (int)acc) * (sc * (0.5f / 255.f));

  __syncthreads();   // clsmax init visible
  if (sc > 0.f) atomicMax(&clsmax[r][lb], __float_as_int(vout));
  __syncthreads();

  if (tid < 8 * NCLS) {
    int rr = tid / NCLS, cc = tid - rr * NCLS;
    int bits = clsmax[rr][cc];
    if (bits != (int)0xFF800000)
      atomicMax(&out_bits[(row0 + rr) * NCLS + cc], bits);
  }
}

extern "C" void kernel_launch(void* const* d_in, const int* in_sizes, int n_in,
                              void* d_out, int out_size, void* d_ws, size_t ws_size,
                              hipStream_t stream) {
  const float* x = (const float*)d_in[0];
  const float* T = (const float*)d_in[1];
  const int* committed = (const int*)d_in[2];
  const int* labels = (const int*)d_in[3];
  const int* counts = (const int*)d_in[4];
  int* out_bits = (int*)d_out;
  float* ws = (float*)d_ws;

  k_minmax<<<dim3(256), dim3(256), 0, stream>>>(x, ws, out_bits);
  k_denom<<<dim3(16), dim3(256), 0, stream>>>(T, committed, counts, ws);
  k_code<<<dim3(64), dim3(256), 0, stream>>>(x, ws);
  k_main<<<dim3(NBLK), dim3(256), 0, stream>>>(labels, ws, out_bits);
}

// Round 19
// 45.347 us; speedup vs baseline: 1.0083x; 1.0083x over previous
//
#include <hip/hip_runtime.h>
#include <math.h>

#define ALPHA 0.001f
#define GAMMA 0.01f
#define DD 784
#define TD 1568          // 2*D floats per template row
#define RB 2048          // padded u8 row bytes (coded & templates)
#define MM 256
#define BB 1024
#define NCLS 10
#define ROWS_PB 4
#define TPW 4
#define NBLK 4096        // 256 rowgroups x 16 tgroups

// ws layout:
//   f32[0..255] partial min | f32[256..511] partial max
//   f32[512..767] scale[m] | f32[768] min | f32[769] 1/(max-min+1e-10)
//   i32[1024..1279] tsum[m]
//   i32[1536..2559] rowsum[row]
//   byte 16384:  u8 templates 256 x 2048  (512 KB)
//   byte 540672: u8 coded    1024 x 2048  (2 MB)

#define TMPL_OFF 16384
#define CODED_OFF 540672

static __device__ __forceinline__ unsigned sad_u8(unsigned a, unsigned b, unsigned c) {
  unsigned d;
  asm("v_sad_u8 %0, %1, %2, %3" : "=v"(d) : "v"(a), "v"(b), "v"(c));
  return d;
}

template <int CTRL, int RMASK>
static __device__ __forceinline__ int dpp_iadd(int v) {
  int t = __builtin_amdgcn_update_dpp(0, v, CTRL, RMASK, 0xf, false);
  return v + t;
}
static __device__ __forceinline__ int wave_isum64_lane63(int v) {
  v = dpp_iadd<0x111, 0xf>(v);   // row_shr:1
  v = dpp_iadd<0x112, 0xf>(v);   // row_shr:2
  v = dpp_iadd<0x114, 0xf>(v);   // row_shr:4
  v = dpp_iadd<0x118, 0xf>(v);   // row_shr:8
  v = dpp_iadd<0x142, 0xa>(v);   // row_bcast:15 -> rows 1,3
  v = dpp_iadd<0x143, 0xc>(v);   // row_bcast:31 -> rows 2,3
  return v;                      // lane 63 = full sum
}

static __device__ __forceinline__ unsigned q8(float v) {
  return (unsigned)(v * 255.f + 0.5f);   // v in [0,1]
}

__global__ __launch_bounds__(256) void k_minmax(const float* __restrict__ x,
                                                float* __restrict__ ws,
                                                int* __restrict__ out_bits) {
  const float4* x4 = (const float4*)x;
  const int n4 = BB * DD / 4;
  int tid = blockIdx.x * 256 + threadIdx.x;
  if (tid < BB * NCLS) out_bits[tid] = (int)0xFF800000;  // -inf each launch
  float mn = 1e30f, mx = -1e30f;
  for (int i = tid; i < n4; i += 256 * 256) {
    float4 v = x4[i];
    mn = fminf(mn, fminf(fminf(v.x, v.y), fminf(v.z, v.w)));
    mx = fmaxf(mx, fmaxf(fmaxf(v.x, v.y), fmaxf(v.z, v.w)));
  }
#pragma unroll
  for (int off = 32; off; off >>= 1) {
    mn = fminf(mn, __shfl_xor(mn, off, 64));
    mx = fmaxf(mx, __shfl_xor(mx, off, 64));
  }
  __shared__ float smn[4], smx[4];
  int lane = threadIdx.x & 63, wid = threadIdx.x >> 6;
  if (lane == 0) { smn[wid] = mn; smx[wid] = mx; }
  __syncthreads();
  if (threadIdx.x == 0) {
    mn = fminf(fminf(smn[0], smn[1]), fminf(smn[2], smn[3]));
    mx = fmaxf(fmaxf(smx[0], smx[1]), fmaxf(smx[2], smx[3]));
    ws[blockIdx.x] = mn;
    ws[256 + blockIdx.x] = mx;
  }
}

__global__ __launch_bounds__(256) void k_stats(float* __restrict__ ws) {
  int tid = threadIdx.x;
  float mn = ws[tid], mx = ws[256 + tid];
#pragma unroll
  for (int off = 32; off; off >>= 1) {
    mn = fminf(mn, __shfl_xor(mn, off, 64));
    mx = fmaxf(mx, __shfl_xor(mx, off, 64));
  }
  __shared__ float smn[4], smx[4];
  int lane = tid & 63, wid = tid >> 6;
  if (lane == 0) { smn[wid] = mn; smx[wid] = mx; }
  __syncthreads();
  if (tid == 0) {
    mn = fminf(fminf(smn[0], smn[1]), fminf(smn[2], smn[3]));
    mx = fmaxf(fmaxf(smx[0], smx[1]), fmaxf(smx[2], smx[3]));
    ws[768] = mn;
    ws[769] = 1.0f / (mx - mn + 1e-10f);
  }
}

// block per template m, 64 threads. Emits f32 scale, int tsum, u8 row.
__global__ __launch_bounds__(64) void k_denom(const float* __restrict__ T,
                                              const int* __restrict__ committed,
                                              const int* __restrict__ counts,
                                              float* __restrict__ ws) {
  int m = blockIdx.x;
  int lane = threadIdx.x;
  float s = 0.f;
  int isum = 0;
  uint4 pk[2] = {make_uint4(0,0,0,0), make_uint4(0,0,0,0)};
  if (lane < 49) {
    const float4* tp = (const float4*)(T + (size_t)m * TD + lane * 32);
    unsigned w[8];
#pragma unroll
    for (int d = 0; d < 8; ++d) {
      float4 f = tp[d];
      s += (f.x + f.y) + (f.z + f.w);
      unsigned b0 = q8(f.x), b1 = q8(f.y), b2 = q8(f.z), b3 = q8(f.w);
      isum += (int)(b0 + b1 + b2 + b3);
      w[d] = b0 | (b1 << 8) | (b2 << 16) | (b3 << 24);
    }
    pk[0] = make_uint4(w[0], w[1], w[2], w[3]);
    pk[1] = make_uint4(w[4], w[5], w[6], w[7]);
  }
  uint4* u8T = (uint4*)((char*)ws + TMPL_OFF + (size_t)m * RB);
  u8T[lane * 2]     = pk[0];
  u8T[lane * 2 + 1] = pk[1];
#pragma unroll
  for (int off = 32; off; off >>= 1) {
    s += __shfl_xor(s, off, 64);
    isum += __shfl_xor(isum, off, 64);
  }
  if (lane == 0) {
    float denom = ALPHA + s + GAMMA * (float)counts[m];
    ws[512 + m] = committed[m] ? (1.0f / denom) : -1.0f;
    ((int*)ws)[1024 + m] = isum;
  }
}

// One-shot quantize+pack of coded x rows. 256 blocks x 256 thr.
__global__ __launch_bounds__(256) void k_code(const float* __restrict__ x,
                                              float* __restrict__ ws) {
  __shared__ int rsum[4];
  int tid = threadIdx.x;
  if (tid < 4) rsum[tid] = 0;
  __syncthreads();
  float fmn = ws[768], finv = ws[769];
  float na = finv, nb = -fmn * finv;
  int row0 = blockIdx.x * 4;
  uint4* out4 = (uint4*)((char*)ws + CODED_OFF) + (size_t)blockIdx.x * 512;
#pragma unroll
  for (int i = 0; i < 2; ++i) {
    int idx = i * 256 + tid;           // 0..511
    int r = idx >> 7;
    int u = idx & 127;
    uint4 o = make_uint4(0, 0, 0, 0);
    if (u < 98) {
      int half = (u >= 49);
      int e = (half ? (u - 49) : u) * 16;
      const float4* xr = (const float4*)(x + (size_t)(row0 + r) * DD + e);
      unsigned w[4];
      int isum = 0;
#pragma unroll
      for (int d = 0; d < 4; ++d) {
        float4 f = xr[d];
        float v0 = na * f.x + nb, v1 = na * f.y + nb;
        float v2 = na * f.z + nb, v3 = na * f.w + nb;
        if (half) { v0 = 1.f - v0; v1 = 1.f - v1; v2 = 1.f - v2; v3 = 1.f - v3; }
        unsigned b0 = q8(v0), b1 = q8(v1), b2 = q8(v2), b3 = q8(v3);
        isum += (int)(b0 + b1 + b2 + b3);
        w[d] = b0 | (b1 << 8) | (b2 << 16) | (b3 << 24);
      }
      o = make_uint4(w[0], w[1], w[2], w[3]);
      atomicAdd(&rsum[r], isum);
    }
    out4[idx] = o;
  }
  __syncthreads();
  if (tid < 4) ((int*)ws)[1536 + row0 + tid] = rsum[tid];
}

// grid: 4096 = 256 rowgroups x 16 tgroups; 256 threads = 4 waves.
// Full prefetch (inline-asm loads), one vmcnt(0) drain, 128 SADs, DPP reduce.
// Launched TWICE (idempotent atomicMax): 2nd dispatch reads L2-warm operands
// -> warm-vs-cold discriminator for the ~22us cost.
__global__ __launch_bounds__(256) void k_main(const int* __restrict__ labels,
                                              const float* __restrict__ ws,
                                              int* __restrict__ out_bits) {
  __shared__ int clsmax[ROWS_PB][NCLS];

  int tid = threadIdx.x;
  int lane = tid & 63, wid = tid >> 6;
  int rg = blockIdx.x >> 4;
  int tg = blockIdx.x & 15;
  int row0 = rg * ROWS_PB;
  int m0 = tg * 16 + wid * TPW;

  // ---- issue ALL loads first: 8 template + 8 coded (inline asm) ----
  const uint4* tbase = (const uint4*)((const char*)ws + TMPL_OFF);
  const uint4* cg = (const uint4*)((const char*)ws + CODED_OFF) + (size_t)row0 * 128;
  uint4 tr[TPW][2], cr[ROWS_PB][2];
#pragma unroll
  for (int t = 0; t < TPW; ++t) {
    const uint4* a0 = tbase + (size_t)(m0 + t) * 128 + lane;
    const uint4* a1 = a0 + 64;
    asm volatile("global_load_dwordx4 %0, %1, off" : "=v"(tr[t][0]) : "v"(a0));
    asm volatile("global_load_dwordx4 %0, %1, off" : "=v"(tr[t][1]) : "v"(a1));
  }
#pragma unroll
  for (int r = 0; r < ROWS_PB; ++r) {
    const uint4* b0 = cg + r * 128 + lane;
    const uint4* b1 = b0 + 64;
    asm volatile("global_load_dwordx4 %0, %1, off" : "=v"(cr[r][0]) : "v"(b0));
    asm volatile("global_load_dwordx4 %0, %1, off" : "=v"(cr[r][1]) : "v"(b1));
  }

  // scalar-ish metadata loads (overlap with VMEM)
  float scv[TPW];
  int lbv[TPW], tsv[TPW];
#pragma unroll
  for (int t = 0; t < TPW; ++t) {
    scv[t] = ws[512 + m0 + t];
    lbv[t] = labels[m0 + t];
    tsv[t] = ((const int*)ws)[1024 + m0 + t];
  }
  int myrow = ((const int*)ws)[1536 + row0 + (lane & 3)];

  if (tid < ROWS_PB * NCLS) clsmax[tid / NCLS][tid % NCLS] = (int)0xFF800000;

  // single drain; fence register-only SAD from hoisting above (rule #18)
  asm volatile("s_waitcnt vmcnt(0)" ::: "memory");
  __builtin_amdgcn_sched_barrier(0);
  __syncthreads();   // clsmax init visible

  // ---- compute: 128 v_sad_u8, zero memory ops ----
  unsigned acc[TPW][ROWS_PB];
#pragma unroll
  for (int t = 0; t < TPW; ++t)
#pragma unroll
    for (int r = 0; r < ROWS_PB; ++r) acc[t][r] = 0;

#pragma unroll
  for (int r = 0; r < ROWS_PB; ++r) {
#pragma unroll
    for (int t = 0; t < TPW; ++t) {
      unsigned a = acc[t][r];
      a = sad_u8(cr[r][0].x, tr[t][0].x, a);
      a = sad_u8(cr[r][0].y, tr[t][0].y, a);
      a = sad_u8(cr[r][0].z, tr[t][0].z, a);
      a = sad_u8(cr[r][0].w, tr[t][0].w, a);
      a = sad_u8(cr[r][1].x, tr[t][1].x, a);
      a = sad_u8(cr[r][1].y, tr[t][1].y, a);
      a = sad_u8(cr[r][1].z, tr[t][1].z, a);
      a = sad_u8(cr[r][1].w, tr[t][1].w, a);
      acc[t][r] = a;
    }
  }

  // ---- reduce: 16 DPP sums; scatter lane = t*4+r computes choice ----
  float sc = -1.f; int lb = 0, tsum_s = 0;
#pragma unroll
  for (int t = 0; t < TPW; ++t)
    if ((lane >> 2) == t) { sc = scv[t]; lb = lbv[t]; tsum_s = tsv[t]; }

  float vout = 0.f;
#pragma unroll
  for (int t = 0; t < TPW; ++t)
#pragma unroll
    for (int r = 0; r < ROWS_PB; ++r) {
      int s = wave_isum64_lane63((int)acc[t][r]);
      int g = __builtin_amdgcn_readlane(s, 63);
      if (lane == t * 4 + r)
        vout = (float)(myrow + tsum_s - g) * (sc * (0.5f / 255.f));
    }

  if (lane < 16 && sc > 0.f)
    atomicMax(&clsmax[lane & 3][lb], __float_as_int(vout));
  __syncthreads();

  if (tid < ROWS_PB * NCLS) {
    int rr = tid / NCLS, cc = tid - rr * NCLS;
    int bits = clsmax[rr][cc];
    if (bits != (int)0xFF800000)
      atomicMax(&out_bits[(row0 + rr) * NCLS + cc], bits);
  }
}

extern "C" void kernel_launch(void* const* d_in, const int* in_sizes, int n_in,
                              void* d_out, int out_size, void* d_ws, size_t ws_size,
                              hipStream_t stream) {
  const float* x = (const float*)d_in[0];
  const float* T = (const float*)d_in[1];
  const int* committed = (const int*)d_in[2];
  const int* labels = (const int*)d_in[3];
  const int* counts = (const int*)d_in[4];
  int* out_bits = (int*)d_out;
  float* ws = (float*)d_ws;

  k_minmax<<<dim3(256), dim3(256), 0, stream>>>(x, ws, out_bits);
  k_stats<<<dim3(1), dim3(256), 0, stream>>>(ws);
  k_denom<<<dim3(256), dim3(64), 0, stream>>>(T, committed, counts, ws);
  k_code<<<dim3(256), dim3(256), 0, stream>>>(x, ws);
  k_main<<<dim3(NBLK), dim3(256), 0, stream>>>(labels, ws, out_bits);
  k_main<<<dim3(NBLK), dim3(256), 0, stream>>>(labels, ws, out_bits);  // warm A/B probe
}

// Round 20
// 35.288 us; speedup vs baseline: 1.2957x; 1.2850x over previous
//
#include <hip/hip_runtime.h>
#include <math.h>

#define ALPHA 0.001f
#define GAMMA 0.01f
#define DD 784
#define TD 1568          // 2*D floats per template row
#define RB 2048          // padded u8 row bytes (templates)
#define MM 256
#define BB 1024
#define NCLS 10
#define ROWS_PB 4
#define TPW 4
#define NBLK 4096        // 256 rowgroups x 16 tgroups

// ws layout:
//   f32[0..255] partial min | f32[256..511] partial max
//   f32[512..767] scale[m] | f32[768] min | f32[769] 1/(max-min+1e-10)
//   i32[1024..1279] tsum[m]
//   byte 16384: u8 templates 256 x 2048 (512 KB)

#define TMPL_OFF 16384

static __device__ __forceinline__ unsigned sad_u8(unsigned a, unsigned b, unsigned c) {
  unsigned d;
  asm("v_sad_u8 %0, %1, %2, %3" : "=v"(d) : "v"(a), "v"(b), "v"(c));
  return d;
}

template <int CTRL, int RMASK>
static __device__ __forceinline__ int dpp_iadd(int v) {
  int t = __builtin_amdgcn_update_dpp(0, v, CTRL, RMASK, 0xf, false);
  return v + t;
}
static __device__ __forceinline__ int wave_isum64_lane63(int v) {
  v = dpp_iadd<0x111, 0xf>(v);   // row_shr:1
  v = dpp_iadd<0x112, 0xf>(v);   // row_shr:2
  v = dpp_iadd<0x114, 0xf>(v);   // row_shr:4
  v = dpp_iadd<0x118, 0xf>(v);   // row_shr:8
  v = dpp_iadd<0x142, 0xa>(v);   // row_bcast:15 -> rows 1,3
  v = dpp_iadd<0x143, 0xc>(v);   // row_bcast:31 -> rows 2,3
  return v;                      // lane 63 = full sum
}

static __device__ __forceinline__ unsigned q8(float v) {
  return (unsigned)(v * 255.f + 0.5f);   // v in [0,1]
}

__global__ __launch_bounds__(256) void k_minmax(const float* __restrict__ x,
                                                float* __restrict__ ws,
                                                int* __restrict__ out_bits) {
  const float4* x4 = (const float4*)x;
  const int n4 = BB * DD / 4;
  int tid = blockIdx.x * 256 + threadIdx.x;
  if (tid < BB * NCLS) out_bits[tid] = (int)0xFF800000;  // -inf each launch
  float mn = 1e30f, mx = -1e30f;
  for (int i = tid; i < n4; i += 256 * 256) {
    float4 v = x4[i];
    mn = fminf(mn, fminf(fminf(v.x, v.y), fminf(v.z, v.w)));
    mx = fmaxf(mx, fmaxf(fmaxf(v.x, v.y), fmaxf(v.z, v.w)));
  }
#pragma unroll
  for (int off = 32; off; off >>= 1) {
    mn = fminf(mn, __shfl_xor(mn, off, 64));
    mx = fmaxf(mx, __shfl_xor(mx, off, 64));
  }
  __shared__ float smn[4], smx[4];
  int lane = threadIdx.x & 63, wid = threadIdx.x >> 6;
  if (lane == 0) { smn[wid] = mn; smx[wid] = mx; }
  __syncthreads();
  if (threadIdx.x == 0) {
    mn = fminf(fminf(smn[0], smn[1]), fminf(smn[2], smn[3]));
    mx = fmaxf(fmaxf(smx[0], smx[1]), fmaxf(smx[2], smx[3]));
    ws[blockIdx.x] = mn;
    ws[256 + blockIdx.x] = mx;
  }
}

// block per template m, 64 threads. Emits f32 scale, int tsum, u8 row.
// Block 0's wave ALSO finalizes the global min/max stats (replaces k_stats;
// independent of this block's template lanes, ordered before k_main).
__global__ __launch_bounds__(64) void k_denom(const float* __restrict__ T,
                                              const int* __restrict__ committed,
                                              const int* __restrict__ counts,
                                              float* __restrict__ ws) {
  int m = blockIdx.x;
  int lane = threadIdx.x;

  if (m == 0) {   // ---- stats finalize (single wave) ----
    float mn = 1e30f, mx = -1e30f;
    for (int i = lane; i < 256; i += 64) {
      mn = fminf(mn, ws[i]);
      mx = fmaxf(mx, ws[256 + i]);
    }
#pragma unroll
    for (int off = 32; off; off >>= 1) {
      mn = fminf(mn, __shfl_xor(mn, off, 64));
      mx = fmaxf(mx, __shfl_xor(mx, off, 64));
    }
    if (lane == 0) {
      ws[768] = mn;
      ws[769] = 1.0f / (mx - mn + 1e-10f);
    }
  }

  float s = 0.f;
  int isum = 0;
  uint4 pk[2] = {make_uint4(0,0,0,0), make_uint4(0,0,0,0)};
  if (lane < 49) {
    const float4* tp = (const float4*)(T + (size_t)m * TD + lane * 32);
    unsigned w[8];
#pragma unroll
    for (int d = 0; d < 8; ++d) {
      float4 f = tp[d];
      s += (f.x + f.y) + (f.z + f.w);
      unsigned b0 = q8(f.x), b1 = q8(f.y), b2 = q8(f.z), b3 = q8(f.w);
      isum += (int)(b0 + b1 + b2 + b3);
      w[d] = b0 | (b1 << 8) | (b2 << 16) | (b3 << 24);
    }
    pk[0] = make_uint4(w[0], w[1], w[2], w[3]);
    pk[1] = make_uint4(w[4], w[5], w[6], w[7]);
  }
  uint4* u8T = (uint4*)((char*)ws + TMPL_OFF + (size_t)m * RB);
  u8T[lane * 2]     = pk[0];
  u8T[lane * 2 + 1] = pk[1];
#pragma unroll
  for (int off = 32; off; off >>= 1) {
    s += __shfl_xor(s, off, 64);
    isum += __shfl_xor(isum, off, 64);
  }
  if (lane == 0) {
    float denom = ALPHA + s + GAMMA * (float)counts[m];
    ws[512 + m] = committed[m] ? (1.0f / denom) : -1.0f;
    ((int*)ws)[1024 + m] = isum;
  }
}

// grid: 4096 = 256 rowgroups x 16 tgroups; 256 threads = 4 waves.
// FUSED: block quantizes its own 4 rows straight from x (warm input -- no
// ws coded buffer, no cross-XCD migration, no k_code launch) into LDS, then
// runs the R17 core: asm template prefetch, one drain, 128 SADs, DPP reduce.
__global__ __launch_bounds__(256) void k_main(const float* __restrict__ x,
                                              const int* __restrict__ labels,
                                              const float* __restrict__ ws,
                                              int* __restrict__ out_bits) {
  __shared__ uint4 coded[ROWS_PB * 128];   // 4 rows x 2048 B = 8192 B
  __shared__ int rsum[ROWS_PB];
  __shared__ int clsmax[ROWS_PB][NCLS];

  int tid = threadIdx.x;
  int lane = tid & 63, wid = tid >> 6;
  int rg = blockIdx.x >> 4;
  int tg = blockIdx.x & 15;
  int row0 = rg * ROWS_PB;
  int m0 = tg * 16 + wid * TPW;

  // ---- issue template loads first (latency hides under quantize) ----
  const uint4* tbase = (const uint4*)((const char*)ws + TMPL_OFF);
  uint4 tr[TPW][2];
#pragma unroll
  for (int t = 0; t < TPW; ++t) {
    const uint4* a0 = tbase + (size_t)(m0 + t) * 128 + lane;
    const uint4* a1 = a0 + 64;
    asm volatile("global_load_dwordx4 %0, %1, off" : "=v"(tr[t][0]) : "v"(a0));
    asm volatile("global_load_dwordx4 %0, %1, off" : "=v"(tr[t][1]) : "v"(a1));
  }

  float fmn = ws[768], finv = ws[769];
  float na = finv, nb = -fmn * finv;

  float scv[TPW];
  int lbv[TPW], tsv[TPW];
#pragma unroll
  for (int t = 0; t < TPW; ++t) {
    scv[t] = ws[512 + m0 + t];
    lbv[t] = labels[m0 + t];
    tsv[t] = ((const int*)ws)[1024 + m0 + t];
  }

  if (tid < ROWS_PB) rsum[tid] = 0;
  if (tid < ROWS_PB * NCLS) clsmax[tid / NCLS][tid % NCLS] = (int)0xFF800000;
  __syncthreads();   // rsum/clsmax init visible before atomics

  // ---- quantize 4 rows from x into LDS (2 uint4 per thread) ----
  int isum_t = 0;
  int r_mine = (tid * 2) >> 7;     // both of this thread's uint4 are same row
#pragma unroll
  for (int k = 0; k < 2; ++k) {
    int idx = tid * 2 + k;
    int u = idx & 127;
    uint4 o = make_uint4(0, 0, 0, 0);
    if (u < 98) {
      int comp = (u >= 49);
      int jb = comp ? (u - 49) : u;
      const float4* xr = (const float4*)(x + (size_t)(row0 + r_mine) * DD) + jb * 4;
      unsigned w[4];
#pragma unroll
      for (int d = 0; d < 4; ++d) {
        float4 f = xr[d];
        float v0 = na * f.x + nb, v1 = na * f.y + nb;
        float v2 = na * f.z + nb, v3 = na * f.w + nb;
        if (comp) { v0 = 1.f - v0; v1 = 1.f - v1; v2 = 1.f - v2; v3 = 1.f - v3; }
        unsigned b0 = q8(v0), b1 = q8(v1), b2 = q8(v2), b3 = q8(v3);
        isum_t += (int)(b0 + b1 + b2 + b3);
        w[d] = b0 | (b1 << 8) | (b2 << 16) | (b3 << 24);
      }
      o = make_uint4(w[0], w[1], w[2], w[3]);
    }
    coded[idx] = o;
  }
  if (isum_t) atomicAdd(&rsum[r_mine], isum_t);
  __syncthreads();

  // ---- coded rows LDS -> regs (broadcast reads, conflict-free) ----
  uint4 cr[ROWS_PB][2];
#pragma unroll
  for (int r = 0; r < ROWS_PB; ++r) {
    cr[r][0] = coded[r * 128 + lane];
    cr[r][1] = coded[r * 128 + 64 + lane];
  }
  int myrow = rsum[lane & 3];

  // drain template loads; fence register-only SAD from hoisting (rule #18)
  asm volatile("s_waitcnt vmcnt(0)" ::: "memory");
  __builtin_amdgcn_sched_barrier(0);

  // ---- compute: 128 v_sad_u8, zero memory ops ----
  unsigned acc[TPW][ROWS_PB];
#pragma unroll
  for (int t = 0; t < TPW; ++t)
#pragma unroll
    for (int r = 0; r < ROWS_PB; ++r) acc[t][r] = 0;

#pragma unroll
  for (int r = 0; r < ROWS_PB; ++r) {
#pragma unroll
    for (int t = 0; t < TPW; ++t) {
      unsigned a = acc[t][r];
      a = sad_u8(cr[r][0].x, tr[t][0].x, a);
      a = sad_u8(cr[r][0].y, tr[t][0].y, a);
      a = sad_u8(cr[r][0].z, tr[t][0].z, a);
      a = sad_u8(cr[r][0].w, tr[t][0].w, a);
      a = sad_u8(cr[r][1].x, tr[t][1].x, a);
      a = sad_u8(cr[r][1].y, tr[t][1].y, a);
      a = sad_u8(cr[r][1].z, tr[t][1].z, a);
      a = sad_u8(cr[r][1].w, tr[t][1].w, a);
      acc[t][r] = a;
    }
  }

  // ---- reduce: 16 DPP sums; scatter lane = t*4+r computes choice ----
  float sc = -1.f; int lb = 0, tsum_s = 0;
#pragma unroll
  for (int t = 0; t < TPW; ++t)
    if ((lane >> 2) == t) { sc = scv[t]; lb = lbv[t]; tsum_s = tsv[t]; }

  float vout = 0.f;
#pragma unroll
  for (int t = 0; t < TPW; ++t)
#pragma unroll
    for (int r = 0; r < ROWS_PB; ++r) {
      int s = wave_isum64_lane63((int)acc[t][r]);
      int g = __builtin_amdgcn_readlane(s, 63);
      if (lane == t * 4 + r)
        vout = (float)(myrow + tsum_s - g) * (sc * (0.5f / 255.f));
    }

  if (lane < 16 && sc > 0.f)
    atomicMax(&clsmax[lane & 3][lb], __float_as_int(vout));
  __syncthreads();

  if (tid < ROWS_PB * NCLS) {
    int rr = tid / NCLS, cc = tid - rr * NCLS;
    int bits = clsmax[rr][cc];
    if (bits != (int)0xFF800000)
      atomicMax(&out_bits[(row0 + rr) * NCLS + cc], bits);
  }
}

extern "C" void kernel_launch(void* const* d_in, const int* in_sizes, int n_in,
                              void* d_out, int out_size, void* d_ws, size_t ws_size,
                              hipStream_t stream) {
  const float* x = (const float*)d_in[0];
  const float* T = (const float*)d_in[1];
  const int* committed = (const int*)d_in[2];
  const int* labels = (const int*)d_in[3];
  const int* counts = (const int*)d_in[4];
  int* out_bits = (int*)d_out;
  float* ws = (float*)d_ws;

  k_minmax<<<dim3(256), dim3(256), 0, stream>>>(x, ws, out_bits);
  k_denom<<<dim3(256), dim3(64), 0, stream>>>(T, committed, counts, ws);
  k_main<<<dim3(NBLK), dim3(256), 0, stream>>>(x, labels, ws, out_bits);
}

// Round 21
// 29.735 us; speedup vs baseline: 1.5377x; 1.1868x over previous
//
#include <hip/hip_runtime.h>
#include <math.h>

#define ALPHA 0.001f
#define GAMMA 0.01f
#define DD 784
#define TD 1568          // 2*D floats per template row
#define RB 2048          // padded u8 row bytes (coded & templates)
#define MM 256
#define BB 1024
#define NCLS 10
#define ROWS_PB 4
#define TPW 4
#define NBLK 4096        // 16 tgroups (high bits) x 256 rowgroups (low bits)

// ws layout:
//   f32[0..255] partial min | f32[256..511] partial max
//   f32[512..767] scale[m] | f32[768] min | f32[769] 1/(max-min+1e-10)
//   i32[1024..1279] tsum[m]
//   i32[1536..2559] rowsum[row]
//   byte 16384:  u8 templates 256 x 2048  (512 KB)
//   byte 540672: u8 coded    1024 x 2048  (2 MB)

#define TMPL_OFF 16384
#define CODED_OFF 540672

static __device__ __forceinline__ unsigned sad_u8(unsigned a, unsigned b, unsigned c) {
  unsigned d;
  asm("v_sad_u8 %0, %1, %2, %3" : "=v"(d) : "v"(a), "v"(b), "v"(c));
  return d;
}

template <int CTRL, int RMASK>
static __device__ __forceinline__ int dpp_iadd(int v) {
  int t = __builtin_amdgcn_update_dpp(0, v, CTRL, RMASK, 0xf, false);
  return v + t;
}
static __device__ __forceinline__ int wave_isum64_lane63(int v) {
  v = dpp_iadd<0x111, 0xf>(v);   // row_shr:1
  v = dpp_iadd<0x112, 0xf>(v);   // row_shr:2
  v = dpp_iadd<0x114, 0xf>(v);   // row_shr:4
  v = dpp_iadd<0x118, 0xf>(v);   // row_shr:8
  v = dpp_iadd<0x142, 0xa>(v);   // row_bcast:15 -> rows 1,3
  v = dpp_iadd<0x143, 0xc>(v);   // row_bcast:31 -> rows 2,3
  return v;                      // lane 63 = full sum
}

static __device__ __forceinline__ unsigned q8(float v) {
  return (unsigned)(v * 255.f + 0.5f);   // v in [0,1]
}

__global__ __launch_bounds__(256) void k_minmax(const float* __restrict__ x,
                                                float* __restrict__ ws,
                                                int* __restrict__ out_bits) {
  const float4* x4 = (const float4*)x;
  const int n4 = BB * DD / 4;
  int tid = blockIdx.x * 256 + threadIdx.x;
  if (tid < BB * NCLS) out_bits[tid] = (int)0xFF800000;  // -inf each launch
  float mn = 1e30f, mx = -1e30f;
  for (int i = tid; i < n4; i += 256 * 256) {
    float4 v = x4[i];
    mn = fminf(mn, fminf(fminf(v.x, v.y), fminf(v.z, v.w)));
    mx = fmaxf(mx, fmaxf(fmaxf(v.x, v.y), fmaxf(v.z, v.w)));
  }
#pragma unroll
  for (int off = 32; off; off >>= 1) {
    mn = fminf(mn, __shfl_xor(mn, off, 64));
    mx = fmaxf(mx, __shfl_xor(mx, off, 64));
  }
  __shared__ float smn[4], smx[4];
  int lane = threadIdx.x & 63, wid = threadIdx.x >> 6;
  if (lane == 0) { smn[wid] = mn; smx[wid] = mx; }
  __syncthreads();
  if (threadIdx.x == 0) {
    mn = fminf(fminf(smn[0], smn[1]), fminf(smn[2], smn[3]));
    mx = fmaxf(fmaxf(smx[0], smx[1]), fmaxf(smx[2], smx[3]));
    ws[blockIdx.x] = mn;
    ws[256 + blockIdx.x] = mx;
  }
}

// block per template m, 64 threads. Emits f32 scale, int tsum, u8 row.
// Block 0's wave ALSO finalizes the global min/max stats (replaces k_stats;
// k_code runs after this kernel and reads ws[768..769]).
__global__ __launch_bounds__(64) void k_denom(const float* __restrict__ T,
                                              const int* __restrict__ committed,
                                              const int* __restrict__ counts,
                                              float* __restrict__ ws) {
  int m = blockIdx.x;
  int lane = threadIdx.x;

  if (m == 0) {   // ---- stats finalize (single wave) ----
    float mn = 1e30f, mx = -1e30f;
    for (int i = lane; i < 256; i += 64) {
      mn = fminf(mn, ws[i]);
      mx = fmaxf(mx, ws[256 + i]);
    }
#pragma unroll
    for (int off = 32; off; off >>= 1) {
      mn = fminf(mn, __shfl_xor(mn, off, 64));
      mx = fmaxf(mx, __shfl_xor(mx, off, 64));
    }
    if (lane == 0) {
      ws[768] = mn;
      ws[769] = 1.0f / (mx - mn + 1e-10f);
    }
  }

  float s = 0.f;
  int isum = 0;
  uint4 pk[2] = {make_uint4(0,0,0,0), make_uint4(0,0,0,0)};
  if (lane < 49) {
    const float4* tp = (const float4*)(T + (size_t)m * TD + lane * 32);
    unsigned w[8];
#pragma unroll
    for (int d = 0; d < 8; ++d) {
      float4 f = tp[d];
      s += (f.x + f.y) + (f.z + f.w);
      unsigned b0 = q8(f.x), b1 = q8(f.y), b2 = q8(f.z), b3 = q8(f.w);
      isum += (int)(b0 + b1 + b2 + b3);
      w[d] = b0 | (b1 << 8) | (b2 << 16) | (b3 << 24);
    }
    pk[0] = make_uint4(w[0], w[1], w[2], w[3]);
    pk[1] = make_uint4(w[4], w[5], w[6], w[7]);
  }
  uint4* u8T = (uint4*)((char*)ws + TMPL_OFF + (size_t)m * RB);
  u8T[lane * 2]     = pk[0];
  u8T[lane * 2 + 1] = pk[1];
#pragma unroll
  for (int off = 32; off; off >>= 1) {
    s += __shfl_xor(s, off, 64);
    isum += __shfl_xor(isum, off, 64);
  }
  if (lane == 0) {
    float denom = ALPHA + s + GAMMA * (float)counts[m];
    ws[512 + m] = committed[m] ? (1.0f / denom) : -1.0f;
    ((int*)ws)[1024 + m] = isum;
  }
}

// One-shot quantize+pack of coded x rows. 256 blocks x 256 thr; block b
// owns rows 4b..4b+3 -> XCD b%8 (home XCD for that coded slice).
__global__ __launch_bounds__(256) void k_code(const float* __restrict__ x,
                                              float* __restrict__ ws) {
  __shared__ int rsum[4];
  int tid = threadIdx.x;
  if (tid < 4) rsum[tid] = 0;
  __syncthreads();
  float fmn = ws[768], finv = ws[769];
  float na = finv, nb = -fmn * finv;
  int row0 = blockIdx.x * 4;
  uint4* out4 = (uint4*)((char*)ws + CODED_OFF) + (size_t)blockIdx.x * 512;
#pragma unroll
  for (int i = 0; i < 2; ++i) {
    int idx = i * 256 + tid;           // 0..511
    int r = idx >> 7;
    int u = idx & 127;
    uint4 o = make_uint4(0, 0, 0, 0);
    if (u < 98) {
      int half = (u >= 49);
      int e = (half ? (u - 49) : u) * 16;
      const float4* xr = (const float4*)(x + (size_t)(row0 + r) * DD + e);
      unsigned w[4];
      int isum = 0;
#pragma unroll
      for (int d = 0; d < 4; ++d) {
        float4 f = xr[d];
        float v0 = na * f.x + nb, v1 = na * f.y + nb;
        float v2 = na * f.z + nb, v3 = na * f.w + nb;
        if (half) { v0 = 1.f - v0; v1 = 1.f - v1; v2 = 1.f - v2; v3 = 1.f - v3; }
        unsigned b0 = q8(v0), b1 = q8(v1), b2 = q8(v2), b3 = q8(v3);
        isum += (int)(b0 + b1 + b2 + b3);
        w[d] = b0 | (b1 << 8) | (b2 << 16) | (b3 << 24);
      }
      o = make_uint4(w[0], w[1], w[2], w[3]);
      atomicAdd(&rsum[r], isum);
    }
    out4[idx] = o;
  }
  __syncthreads();
  if (tid < 4) ((int*)ws)[1536 + row0 + tid] = rsum[tid];
}

// grid 4096; XCD-ALIGNED decode: rg = bid & 255, tg = bid >> 8.
// All 16 blocks reading rowgroup rg land on XCD (tg*256+rg)%8 = rg%8 --
// the SAME XCD where k_code block rg wrote that coded slice. The 2 MB
// coded buffer never crosses XCDs (R19 measured ~8us/launch migration).
// Core identical to R17/R19: asm prefetch, one drain, 128 SADs, DPP reduce.
__global__ __launch_bounds__(256) void k_main(const int* __restrict__ labels,
                                              const float* __restrict__ ws,
                                              int* __restrict__ out_bits) {
  __shared__ int clsmax[ROWS_PB][NCLS];

  int tid = threadIdx.x;
  int lane = tid & 63, wid = tid >> 6;
  int rg = blockIdx.x & 255;       // low bits -> XCD affinity follows rowgroup
  int tg = blockIdx.x >> 8;
  int row0 = rg * ROWS_PB;
  int m0 = tg * 16 + wid * TPW;

  // ---- issue ALL loads first: 8 template + 8 coded (inline asm) ----
  const uint4* tbase = (const uint4*)((const char*)ws + TMPL_OFF);
  const uint4* cg = (const uint4*)((const char*)ws + CODED_OFF) + (size_t)row0 * 128;
  uint4 tr[TPW][2], cr[ROWS_PB][2];
#pragma unroll
  for (int t = 0; t < TPW; ++t) {
    const uint4* a0 = tbase + (size_t)(m0 + t) * 128 + lane;
    const uint4* a1 = a0 + 64;
    asm volatile("global_load_dwordx4 %0, %1, off" : "=v"(tr[t][0]) : "v"(a0));
    asm volatile("global_load_dwordx4 %0, %1, off" : "=v"(tr[t][1]) : "v"(a1));
  }
#pragma unroll
  for (int r = 0; r < ROWS_PB; ++r) {
    const uint4* b0 = cg + r * 128 + lane;
    const uint4* b1 = b0 + 64;
    asm volatile("global_load_dwordx4 %0, %1, off" : "=v"(cr[r][0]) : "v"(b0));
    asm volatile("global_load_dwordx4 %0, %1, off" : "=v"(cr[r][1]) : "v"(b1));
  }

  // scalar-ish metadata loads (overlap with VMEM)
  float scv[TPW];
  int lbv[TPW], tsv[TPW];
#pragma unroll
  for (int t = 0; t < TPW; ++t) {
    scv[t] = ws[512 + m0 + t];
    lbv[t] = labels[m0 + t];
    tsv[t] = ((const int*)ws)[1024 + m0 + t];
  }
  int myrow = ((const int*)ws)[1536 + row0 + (lane & 3)];

  if (tid < ROWS_PB * NCLS) clsmax[tid / NCLS][tid % NCLS] = (int)0xFF800000;

  // single drain; fence register-only SAD from hoisting above (rule #18)
  asm volatile("s_waitcnt vmcnt(0)" ::: "memory");
  __builtin_amdgcn_sched_barrier(0);
  __syncthreads();   // clsmax init visible

  // ---- compute: 128 v_sad_u8, zero memory ops ----
  unsigned acc[TPW][ROWS_PB];
#pragma unroll
  for (int t = 0; t < TPW; ++t)
#pragma unroll
    for (int r = 0; r < ROWS_PB; ++r) acc[t][r] = 0;

#pragma unroll
  for (int r = 0; r < ROWS_PB; ++r) {
#pragma unroll
    for (int t = 0; t < TPW; ++t) {
      unsigned a = acc[t][r];
      a = sad_u8(cr[r][0].x, tr[t][0].x, a);
      a = sad_u8(cr[r][0].y, tr[t][0].y, a);
      a = sad_u8(cr[r][0].z, tr[t][0].z, a);
      a = sad_u8(cr[r][0].w, tr[t][0].w, a);
      a = sad_u8(cr[r][1].x, tr[t][1].x, a);
      a = sad_u8(cr[r][1].y, tr[t][1].y, a);
      a = sad_u8(cr[r][1].z, tr[t][1].z, a);
      a = sad_u8(cr[r][1].w, tr[t][1].w, a);
      acc[t][r] = a;
    }
  }

  // ---- reduce: 16 DPP sums; scatter lane = t*4+r computes choice ----
  float sc = -1.f; int lb = 0, tsum_s = 0;
#pragma unroll
  for (int t = 0; t < TPW; ++t)
    if ((lane >> 2) == t) { sc = scv[t]; lb = lbv[t]; tsum_s = tsv[t]; }

  float vout = 0.f;
#pragma unroll
  for (int t = 0; t < TPW; ++t)
#pragma unroll
    for (int r = 0; r < ROWS_PB; ++r) {
      int s = wave_isum64_lane63((int)acc[t][r]);
      int g = __builtin_amdgcn_readlane(s, 63);
      if (lane == t * 4 + r)
        vout = (float)(myrow + tsum_s - g) * (sc * (0.5f / 255.f));
    }

  if (lane < 16 && sc > 0.f)
    atomicMax(&clsmax[lane & 3][lb], __float_as_int(vout));
  __syncthreads();

  if (tid < ROWS_PB * NCLS) {
    int rr = tid / NCLS, cc = tid - rr * NCLS;
    int bits = clsmax[rr][cc];
    if (bits != (int)0xFF800000)
      atomicMax(&out_bits[(row0 + rr) * NCLS + cc], bits);
  }
}

extern "C" void kernel_launch(void* const* d_in, const int* in_sizes, int n_in,
                              void* d_out, int out_size, void* d_ws, size_t ws_size,
                              hipStream_t stream) {
  const float* x = (const float*)d_in[0];
  const float* T = (const float*)d_in[1];
  const int* committed = (const int*)d_in[2];
  const int* labels = (const int*)d_in[3];
  const int* counts = (const int*)d_in[4];
  int* out_bits = (int*)d_out;
  float* ws = (float*)d_ws;

  k_minmax<<<dim3(256), dim3(256), 0, stream>>>(x, ws, out_bits);
  k_denom<<<dim3(256), dim3(64), 0, stream>>>(T, committed, counts, ws);
  k_code<<<dim3(256), dim3(256), 0, stream>>>(x, ws);
  k_main<<<dim3(NBLK), dim3(256), 0, stream>>>(labels, ws, out_bits);
}